// Round 8
// baseline (586.901 us; speedup 1.0000x reference)
//
#include <hip/hip_runtime.h>

// Problem constants (from reference): B=32, N=8192, C=512, K=128
#define PB 32
#define PN 8192
#define PC 512
#define PK 128

typedef float vfloat4 __attribute__((ext_vector_type(4)));  // native vec for nt builtins

// Dtype model (validated R4): one_hot f32, id i32, d_out f32 (B*N ++ B*K).
//
// Window decomposition (R4/R5/R7): dur_us is dominated by harness restore
// traffic (2.147 GB d_ws re-poison at 79-81% HBM peak = ~335 us, + ~165 us
// one_hot restore). Our kernels are ~10-20 us; residue is launch overhead +
// the gather->compact stream dependency. R5's fused attempt paid ~60 us for
// agent-scope fence/spin; this version fuses WITHOUT any synchronization:
// compact blocks re-gather directly from one_hot (read-only), so gather and
// compact blocks are fully independent inside one 288-block launch.

__global__ __launch_bounds__(256) void fused_filter(
    const float* __restrict__ one_hot,
    const int* __restrict__ id_ptr,
    float* __restrict__ out0,
    float* __restrict__ out1)
{
    const int g   = blockIdx.x;
    const int tid = threadIdx.x;
    const int id  = id_ptr[0];

    if (g < 256) {
        // ---- gather: 4 elements/thread, 4 independent NT loads ----
        const int t    = g * 256 + tid;       // 0 .. 65535
        const int base = t * 4;               // first of 4 consecutive n
        const float* p = one_hot + (size_t)base * PC + (size_t)id;
        float v0 = __builtin_nontemporal_load(p);
        float v1 = __builtin_nontemporal_load(p + PC);
        float v2 = __builtin_nontemporal_load(p + 2 * PC);
        float v3 = __builtin_nontemporal_load(p + 3 * PC);
        vfloat4 o = { v0, v1, v2, v3 };
        __builtin_nontemporal_store(o, (vfloat4*)(out0 + base));
        return;                               // block-uniform exit
    }

    // ---- compact: one block per batch, reads one_hot directly ----
    const int b    = g - 256;                 // 0..31
    const int wave = tid >> 6;                // 0..3
    const int lane = tid & 63;

    __shared__ unsigned int wave_cnt[4];

    // Prefetch all 32 strided values (independent loads, all in flight).
    const float* rowbase = one_hot + (size_t)b * PN * PC + (size_t)id;
    float vals[32];
#pragma unroll
    for (int ph = 0; ph < 32; ++ph)
        vals[ph] = rowbase[(size_t)(ph * 256 + tid) * PC];

    unsigned int running = 0;  // ones seen in phases < ph
#pragma unroll
    for (int ph = 0; ph < 32; ++ph) {
        const bool pred = (vals[ph] != 0.0f);
        const unsigned long long mask = __ballot(pred);
        if (lane == 0) wave_cnt[wave] = (unsigned int)__popcll(mask);
        __syncthreads();

        unsigned int prefix = 0, total = 0;
#pragma unroll
        for (int w = 0; w < 4; ++w) {
            unsigned int c = wave_cnt[w];
            if (w < wave) prefix += c;
            total += c;
        }

        if (pred) {
            unsigned int rank = (unsigned int)__popcll(mask & ((1ULL << lane) - 1ULL));
            unsigned int pos  = running + prefix + rank;
            if (pos < PK) {
                out1[b * PK + pos] = (float)(ph * 256 + tid);  // ascending n == stable
            }
        }
        running += total;
        __syncthreads();  // protect wave_cnt before next phase
    }
}

extern "C" void kernel_launch(void* const* d_in, const int* in_sizes, int n_in,
                              void* d_out, int out_size, void* d_ws, size_t ws_size,
                              hipStream_t stream) {
    // Resolve inputs by size: the 1-element input is `id`, the big one is one_hot.
    const float* one_hot = nullptr;
    const int* id_ptr = nullptr;
    for (int i = 0; i < n_in; ++i) {
        if (in_sizes[i] == 1) id_ptr = (const int*)d_in[i];
        else                  one_hot = (const float*)d_in[i];
    }

    float* out0 = (float*)d_out;                    // B*N floats
    float* out1 = (float*)d_out + (size_t)PB * PN;  // B*K floats

    fused_filter<<<dim3(256 + PB), dim3(256), 0, stream>>>(one_hot, id_ptr, out0, out1);
}

// Round 9
// 567.636 us; speedup vs baseline: 1.0339x; 1.0339x over previous
//
#include <hip/hip_runtime.h>

// Problem constants (from reference): B=32, N=8192, C=512, K=128
#define PB 32
#define PN 8192
#define PC 512
#define PK 128

typedef float vfloat4 __attribute__((ext_vector_type(4)));  // native vec for nt builtins

// Dtype model (validated R4): one_hot f32, id i32, d_out f32 (B*N ++ B*K).
//
// Final structure (R4..R8 measured): two-kernel split is optimal.
//   R4 simple split: 575 | R7 this kernel: 567 | R5 fused+fence: 629 |
//   R8 fused no-sync (32-block re-gather): 587.
// The timed window is ~86% harness restore traffic (2.147 GB d_ws re-poison
// at ~80% HBM peak = ~335 us + 512 MB one_hot restore ~165 us); our two
// dispatches are ~15 us. Fusion attempts only add tail latency (R8) or
// fence cost (R5). This is the harness-bound floor.

// Kernel A: gather column `id`. 4 elements per thread: 4 independent
// non-temporal loads (2 KB apart, one 64B line each, zero reuse) + one
// coalesced float4 non-temporal store. 256 blocks x 256 threads.
__global__ __launch_bounds__(256) void gather_col(
    const float* __restrict__ one_hot,
    const int* __restrict__ id_ptr,
    float* __restrict__ out0)
{
    const int t    = blockIdx.x * 256 + threadIdx.x;  // 0 .. 65535
    const int base = t * 4;                           // first of 4 consecutive n
    const int id   = id_ptr[0];

    const float* p = one_hot + (size_t)base * PC + (size_t)id;
    float v0 = __builtin_nontemporal_load(p);
    float v1 = __builtin_nontemporal_load(p + PC);
    float v2 = __builtin_nontemporal_load(p + 2 * PC);
    float v3 = __builtin_nontemporal_load(p + 3 * PC);

    vfloat4 o = { v0, v1, v2, v3 };
    __builtin_nontemporal_store(o, (vfloat4*)(out0 + base));
}

// Kernel B: per-batch stable compaction of positions where col != 0.
// One block per batch, 1024 threads, 8 phases of 1024 positions each.
// Ascending n == stable argsort of the 0/1 key, first K (exactly K ones/row).
// Reads the coalesced L2-hot out0 (1 MB) -- NOT the strided one_hot (R8
// showed a 32-block strided re-gather costs +20 us of tail latency).
__global__ __launch_bounds__(1024) void compact_idx(
    const float* __restrict__ out0,
    float* __restrict__ out1)                    // indices as float32
{
    const int b    = blockIdx.x;
    const int tid  = threadIdx.x;
    const int wave = tid >> 6;
    const int lane = tid & 63;

    __shared__ unsigned int wave_cnt[16];

    const float* row = out0 + (size_t)b * PN;

    // Prefetch all 8 values (independent coalesced loads, all in flight).
    float vals[8];
#pragma unroll
    for (int p = 0; p < 8; ++p)
        vals[p] = row[p * 1024 + tid];

    unsigned int running = 0;  // global running count of ones so far
#pragma unroll
    for (int p = 0; p < 8; ++p) {
        const bool pred = (vals[p] != 0.0f);
        const unsigned long long mask = __ballot(pred);
        if (lane == 0) wave_cnt[wave] = (unsigned int)__popcll(mask);
        __syncthreads();

        // 16-wave scan: every thread reads all counts (LDS broadcast reads).
        unsigned int prefix = 0, total = 0;
#pragma unroll
        for (int w = 0; w < 16; ++w) {
            unsigned int c = wave_cnt[w];
            total += c;
            if (w < wave) prefix += c;
        }

        if (pred) {
            unsigned int rank = (unsigned int)__popcll(mask & ((1ULL << lane) - 1ULL));
            unsigned int pos  = running + prefix + rank;
            if (pos < PK) {
                out1[b * PK + pos] = (float)(p * 1024 + tid);
            }
        }
        running += total;
        __syncthreads();  // protect wave_cnt before next phase overwrites it
    }
}

extern "C" void kernel_launch(void* const* d_in, const int* in_sizes, int n_in,
                              void* d_out, int out_size, void* d_ws, size_t ws_size,
                              hipStream_t stream) {
    // Resolve inputs by size: the 1-element input is `id`, the big one is one_hot.
    const float* one_hot = nullptr;
    const int* id_ptr = nullptr;
    for (int i = 0; i < n_in; ++i) {
        if (in_sizes[i] == 1) id_ptr = (const int*)d_in[i];
        else                  one_hot = (const float*)d_in[i];
    }

    float* out0 = (float*)d_out;                    // B*N floats
    float* out1 = (float*)d_out + (size_t)PB * PN;  // B*K floats

    gather_col<<<dim3((PB * PN) / (256 * 4)), dim3(256), 0, stream>>>(one_hot, id_ptr, out0);
    compact_idx<<<dim3(PB), dim3(1024), 0, stream>>>(out0, out1);
}